// Round 20
// baseline (70.045 us; speedup 1.0000x reference)
//
#include <hip/hip_runtime.h>

#define NPTS  4096
#define KNN   16
#define K1    17            // KNN + self
#define NBLK  64            // candidate blocks per batch == wave width
#define CELLS 4096          // 16^3 Morton cells
#define EPSF  1e-10f

__device__ __forceinline__ unsigned umin_(unsigned a, unsigned b) { return a < b ? a : b; }
__device__ __forceinline__ unsigned umax_(unsigned a, unsigned b) { return a < b ? b : a; }
__device__ __forceinline__ unsigned rdlane(unsigned v, int l) {
    return (unsigned)__builtin_amdgcn_readlane((int)v, l);
}

// cheap cross-lane primitives (DPP = VALU, ds_swizzle = DS pipe, shfl = ds_permute)
#define DPP_XOR1(v)  ((unsigned)__builtin_amdgcn_update_dpp(0, (int)(v), 0xB1, 0xF, 0xF, true))
#define DPP_XOR2(v)  ((unsigned)__builtin_amdgcn_update_dpp(0, (int)(v), 0x4E, 0xF, 0xF, true))
#define SWZ_XOR(v,J) ((unsigned)__builtin_amdgcn_ds_swizzle((int)(v), ((J) << 10) | 0x1F))
#define DPP_SHR1(v)  ((unsigned)__builtin_amdgcn_update_dpp(0, (int)(v), 0x111, 0xF, 0xF, true))
#define DPPF_SHR(vf, CTRL) __uint_as_float((unsigned)__builtin_amdgcn_update_dpp(0, (int)__float_as_uint(vf), CTRL, 0xF, 0xF, true))
#define LXOR1(v)  DPP_XOR1(v)
#define LXOR2(v)  DPP_XOR2(v)
#define LXOR4(v)  SWZ_XOR(v, 4)
#define LXOR8(v)  SWZ_XOR(v, 8)
#define LXOR16(v) SWZ_XOR(v, 16)
#define LXOR32(v) ((unsigned)__shfl_xor((int)(v), 32))

// one compare-exchange stage applied to BOTH sort chains (ILP)
#define BSTEP(K, XORF) do {                                                   \
    unsigned o1_ = XORF(arr), o2_ = XORF(bk);                                 \
    bool tm_ = (((lane & (J_)) == 0) == ((lane & (K)) == 0));                 \
    unsigned mn1_ = umin_(arr, o1_), mx1_ = umax_(arr, o1_);                  \
    unsigned mn2_ = umin_(bk, o2_),  mx2_ = umax_(bk, o2_);                   \
    arr = tm_ ? mn1_ : mx1_; bk = tm_ ? mn2_ : mx2_;                          \
} while (0)

// spread 4 bits to positions 0,3,6,9
__device__ __forceinline__ unsigned sp4(int v) {
    unsigned x = (unsigned)v;
    return (x & 1u) | ((x & 2u) << 2) | ((x & 4u) << 4) | ((x & 8u) << 6);
}

// ---- Kernel 1a: Morton cell per point + global per-batch histogram.
// (Counting sort parallelized chip-wide; previously 1 block/batch on 8 CUs.)
__global__ __launch_bounds__(512) void hist_kernel(
    const float* __restrict__ pref, unsigned short* __restrict__ cells,
    unsigned* __restrict__ hist)
{
    const int b = blockIdx.x >> 3;
    const int p = (blockIdx.x & 7) * 512 + threadIdx.x;
    const float* prb = pref + (size_t)b * NPTS * 3;
    float x = prb[3 * p + 0], y = prb[3 * p + 1], z = prb[3 * p + 2];
    int cx = min(15, max(0, (int)((x + 4.0f) * 2.0f)));
    int cy = min(15, max(0, (int)((y + 4.0f) * 2.0f)));
    int cz = min(15, max(0, (int)((z + 4.0f) * 2.0f)));
    unsigned m = sp4(cx) | (sp4(cy) << 1) | (sp4(cz) << 2);
    cells[(size_t)b * NPTS + p] = (unsigned short)m;
    atomicAdd(&hist[(size_t)b * CELLS + m], 1u);
}

// ---- Kernel 1b: per-batch exclusive scan of hist[4096] (in place).
__global__ __launch_bounds__(1024) void scan_kernel(unsigned* __restrict__ hist)
{
    __shared__ unsigned wofs[16];
    const int tid  = threadIdx.x;
    const int lane = tid & 63, w = tid >> 6;
    unsigned* hb = hist + (size_t)blockIdx.x * CELLS;

    unsigned l0 = hb[4 * tid + 0], l1 = hb[4 * tid + 1];
    unsigned l2 = hb[4 * tid + 2], l3 = hb[4 * tid + 3];
    unsigned s = l0 + l1 + l2 + l3;
    unsigned run = s;
#pragma unroll
    for (int d = 1; d < 64; d <<= 1) {
        unsigned o = __shfl_up(run, d);
        if (lane >= d) run += o;
    }
    if (lane == 63) wofs[w] = run;
    __syncthreads();
    if (tid == 0) {
        unsigned acc = 0;
#pragma unroll
        for (int k = 0; k < 16; ++k) { unsigned t2 = wofs[k]; wofs[k] = acc; acc += t2; }
    }
    __syncthreads();
    unsigned excl = wofs[w] + run - s;
    hb[4 * tid + 0] = excl;
    hb[4 * tid + 1] = excl + l0;
    hb[4 * tid + 2] = excl + l0 + l1;
    hb[4 * tid + 3] = excl + l0 + l1 + l2;
}

// ---- Kernel 1c: scatter into sorted order (atomic slot per cell).
// Order within a cell is nondeterministic but it's still a permutation ->
// exactness of the KNN never depends on it.
__global__ __launch_bounds__(512) void scatter_kernel(
    const float* __restrict__ pref, const unsigned short* __restrict__ cells,
    unsigned* __restrict__ hist, float4* __restrict__ wxyzw, int* __restrict__ widx)
{
    const int b = blockIdx.x >> 3;
    const int p = (blockIdx.x & 7) * 512 + threadIdx.x;
    const size_t base = (size_t)b * NPTS;
    const float* prb = pref + (size_t)b * NPTS * 3;
    unsigned c = cells[base + p];
    unsigned pos = atomicAdd(&hist[(size_t)b * CELLS + c], 1u);
    wxyzw[base + pos] = make_float4(prb[3 * p + 0], prb[3 * p + 1], prb[3 * p + 2], 0.f);
    widx[base + pos]  = p;
}

// ---- Kernel 1d: per-64-block bboxes, one bbox per wave (chip-parallel).
__global__ __launch_bounds__(512) void bbox_kernel(
    const float4* __restrict__ wxyzw, float4* __restrict__ wbb)
{
    const int lane = threadIdx.x & 63;
    const int gb = blockIdx.x * 8 + (threadIdx.x >> 6);   // global bbox id
    const int b  = gb >> 6;                                // NBLK per batch
    const int blk = gb & (NBLK - 1);
    const size_t base = (size_t)b * NPTS;

    float4 c = wxyzw[base + blk * 64 + lane];
    float mnx = c.x, mxx = c.x, mny = c.y, mxy2 = c.y, mnz = c.z, mxz = c.z;
#pragma unroll
    for (int d = 32; d > 0; d >>= 1) {
        mnx  = fminf(mnx,  __shfl_xor(mnx,  d));
        mxx  = fmaxf(mxx,  __shfl_xor(mxx,  d));
        mny  = fminf(mny,  __shfl_xor(mny,  d));
        mxy2 = fmaxf(mxy2, __shfl_xor(mxy2, d));
        mnz  = fminf(mnz,  __shfl_xor(mnz,  d));
        mxz  = fmaxf(mxz,  __shfl_xor(mxz,  d));
    }
    if (lane == 0) {
        wbb[(size_t)gb * 2 + 0] = make_float4(mnx, mny, mnz, 0.f);
        wbb[(size_t)gb * 2 + 1] = make_float4(mxx, mxy2, mxz, 0.f);
    }
}

// DPP-based insertion of broadcast key kk_ into lane-sliced sorted arr
#define EVENTS(KEY) do {                                                      \
    unsigned long long m_ = __ballot((KEY) < thr);                            \
    if (m_) {                                                                 \
        do {                                                                  \
            int l_ = __ffsll(m_) - 1;                                         \
            m_ &= m_ - 1;                                                     \
            unsigned kk_ = rdlane(KEY, l_);                                   \
            unsigned long long lt_ = __ballot(arr < kk_) & 0x1FFFFull;        \
            int pos_ = __popcll(lt_);                                         \
            unsigned up_ = DPP_SHR1(arr);                                     \
            unsigned a15_ = rdlane(arr, 15);                                  \
            up_ = (lane == 16) ? a15_ : up_;                                  \
            arr = (lane == pos_) ? kk_ : ((lane > pos_) ? up_ : arr);         \
        } while (m_);                                                         \
        thr = rdlane(arr, K1 - 1);                                            \
    } } while (0)

// ---- Kernel 2: R10 main verbatim (one query per wave, hash-permuted;
// distance-ordered bbox walk with early exit; exact top-17); one contiguous
// partial per block.
__global__ __launch_bounds__(256, 8) void knn_main_kernel(
    const float* __restrict__ ppred,
    const float4* __restrict__ wxyzw, const int* __restrict__ widx,
    const float4* __restrict__ wbb, float* __restrict__ partials, int NQ)
{
    __shared__ float wsum[4];
    const int lane = threadIdx.x & 63;
    const int w    = threadIdx.x >> 6;
    const int wv   = blockIdx.x * 4 + w;
    // odd multiplier mod pow2 is a bijection; mixes spatial regions across waves
    const int q = ((NQ & (NQ - 1)) == 0) ? (int)(((unsigned)wv * 26765u) & (unsigned)(NQ - 1)) : wv;

    const int b = q >> 12;
    const int p = q & (NPTS - 1);              // sorted position = query
    const size_t base = (size_t)b * NPTS;
    const int p0 = p & ~63, ownblk = p >> 6;

    const float4 qc = wxyzw[base + p];         // uniform -> broadcast
    const float qx = qc.x, qy = qc.y, qz = qc.z;

    // own-block candidate keys (self d2 == +0.0 -> key = p = minimum)
    unsigned arr;
    {
        float4 c = wxyzw[base + p0 + lane];
        float dx = c.x - qx, dy = c.y - qy, dz = c.z - qz;
        float d2 = dx * dx + dy * dy + dz * dz;
        arr = (__float_as_uint(d2) & 0xFFFFF000u) | (unsigned)(p0 + lane);
    }
    // bbox lower-bound keys: same truncation as real keys; blk in the index
    // field (blk <= any j in block) => bkey <= every real key in the block.
    unsigned bk;
    {
        float4 mn4 = wbb[((size_t)b * NBLK + lane) * 2 + 0];
        float4 mx4 = wbb[((size_t)b * NBLK + lane) * 2 + 1];
        float ddx = fmaxf(fmaxf(mn4.x - qx, qx - mx4.x), 0.0f);
        float ddy = fmaxf(fmaxf(mn4.y - qy, qy - mx4.y), 0.0f);
        float ddz = fmaxf(fmaxf(mn4.z - qz, qz - mx4.z), 0.0f);
        float bd2 = ddx * ddx + ddy * ddy + ddz * ddz;
        bk = (__float_as_uint(bd2) & 0xFFFFF000u) | (unsigned)lane;
        bk = (lane == ownblk) ? 0xFFFFFFFFu : bk;   // sentinel: never walked
    }

    // joint bitonic sort of arr and bk (ascending), ILP'd through one network
    {
        int J_;
        J_ = 1;  BSTEP(2,  LXOR1);
        J_ = 2;  BSTEP(4,  LXOR2);  J_ = 1; BSTEP(4,  LXOR1);
        J_ = 4;  BSTEP(8,  LXOR4);  J_ = 2; BSTEP(8,  LXOR2);  J_ = 1; BSTEP(8,  LXOR1);
        J_ = 8;  BSTEP(16, LXOR8);  J_ = 4; BSTEP(16, LXOR4);  J_ = 2; BSTEP(16, LXOR2);  J_ = 1; BSTEP(16, LXOR1);
        J_ = 16; BSTEP(32, LXOR16); J_ = 8; BSTEP(32, LXOR8);  J_ = 4; BSTEP(32, LXOR4);  J_ = 2; BSTEP(32, LXOR2); J_ = 1; BSTEP(32, LXOR1);
        J_ = 32; BSTEP(64, LXOR32); J_ = 16; BSTEP(64, LXOR16); J_ = 8; BSTEP(64, LXOR8); J_ = 4; BSTEP(64, LXOR4); J_ = 2; BSTEP(64, LXOR2); J_ = 1; BSTEP(64, LXOR1);
    }
    unsigned thr = rdlane(arr, K1 - 1);

    // ordered walk: blocks by ascending lower bound; break = prune rest (exact:
    // truncation is monotone, bkey <= real keys, thr only decreases).
    int k = 0;
    unsigned bcur = rdlane(bk, 0);
    bool have = (bcur < thr);
    float4 cur;
    if (have) cur = wxyzw[base + (int)(bcur & 0xFFFu) * 64 + lane];
    while (have) {
        unsigned bnext = rdlane(bk, k + 1);
        bool pf = (bnext < thr);               // prefetch decision (conservative)
        float4 nxt;
        if (pf) nxt = wxyzw[base + (int)(bnext & 0xFFFu) * 64 + lane];
        int jbase = (int)(bcur & 0xFFFu) * 64;
        float dx = cur.x - qx, dy = cur.y - qy, dz = cur.z - qz;
        float d2 = dx * dx + dy * dy + dz * dz;
        unsigned key = (__float_as_uint(d2) & 0xFFFFF000u) | (unsigned)(jbase + lane);
        EVENTS(key);                           // tightens thr
        ++k;
        bcur = bnext;
        have = (bcur < thr);                   // thr only decreased: pf false => have false
        cur = nxt;
    }

    // Epilogue: lanes 1..16 hold the 16 nearest neighbors (lane 0 = self).
    const float* ppb = ppred + (size_t)b * NPTS * 3;
    const int iorig = widx[base + p];
    float s = 0.f;
    if (lane >= 1 && lane <= KNN) {
        int js = (int)(arr & 0xFFFu);
        float4 rc = wxyzw[base + js];
        float rx = rc.x - qx, ry = rc.y - qy, rz = rc.z - qz;
        float dref = sqrtf(rx * rx + ry * ry + rz * rz);
        int nj = widx[base + js];
        float px = ppb[3 * iorig + 0], py = ppb[3 * iorig + 1], pz = ppb[3 * iorig + 2];
        float ax = ppb[3 * nj + 0] - px;
        float ay = ppb[3 * nj + 1] - py;
        float az = ppb[3 * nj + 2] - pz;
        float dpred = sqrtf(ax * ax + ay * ay + az * az);
        s = fmaxf(dpred / (dref + EPSF) - 1.0f, 0.0f);
    }
    // DPP prefix-add within rows of 16; lanes 0..16 hold all nonzeros.
    s += DPPF_SHR(s, 0x111);
    s += DPPF_SHR(s, 0x112);
    s += DPPF_SHR(s, 0x114);
    s += DPPF_SHR(s, 0x118);
    float t15 = __uint_as_float(rdlane(__float_as_uint(s), 15));
    float t16 = __uint_as_float(rdlane(__float_as_uint(s), 16));

    // one partial per block (contiguous) -> cheap reduce
    if (lane == 0) wsum[w] = t15 + t16;
    __syncthreads();
    if (threadIdx.x == 0)
        partials[blockIdx.x] = (wsum[0] + wsum[1]) + (wsum[2] + wsum[3]);
}

// ---- Kernel 3: deterministic single-block final reduction (float4 loads).
__global__ __launch_bounds__(1024) void reduce_kernel(
    const float* __restrict__ partials, int n, float* __restrict__ out, float scale)
{
    __shared__ float wsum[16];
    const float4* p4 = (const float4*)partials;
    const int n4 = n >> 2;
    float s = 0.f;
    for (int idx = threadIdx.x; idx < n4; idx += 1024) {
        float4 v = p4[idx];
        s += (v.x + v.y) + (v.z + v.w);
    }
    for (int off = 32; off > 0; off >>= 1) s += __shfl_down(s, off);
    if ((threadIdx.x & 63) == 0) wsum[threadIdx.x >> 6] = s;
    __syncthreads();
    if (threadIdx.x == 0) {
        float t = 0.f;
#pragma unroll
        for (int k = 0; k < 16; ++k) t += wsum[k];
        out[0] = t * scale;
    }
}

extern "C" void kernel_launch(void* const* d_in, const int* in_sizes, int n_in,
                              void* d_out, int out_size, void* d_ws, size_t ws_size,
                              hipStream_t stream) {
    const float* pref  = (const float*)d_in[0];
    const float* ppred = (const float*)d_in[1];
    float* out = (float*)d_out;

    const int B  = in_sizes[0] / (NPTS * 3);
    const int NQ = B * NPTS;
    const int nblocks = NQ / 4;            // 4 waves/block, 1 query/wave
    const float scale = 1.0f / ((float)NQ * (float)KNN);

    char* ws = (char*)d_ws;
    size_t off = 0;
    float4* wxyzw = (float4*)(ws + off);           off += (size_t)B * NPTS * 16;
    int*    widx  = (int*)   (ws + off);           off += (size_t)B * NPTS * 4;
    float4* wbb   = (float4*)(ws + off);           off += (size_t)B * NBLK * 32;
    float*  partials = (float*)(ws + off);         off += (size_t)nblocks * 4;
    unsigned short* cells = (unsigned short*)(ws + off); off += (size_t)B * NPTS * 2;
    unsigned* hist = (unsigned*)(ws + off);        // B*CELLS*4

    hipMemsetAsync(hist, 0, (size_t)B * CELLS * sizeof(unsigned), stream);
    hist_kernel<<<dim3(B * 8), dim3(512), 0, stream>>>(pref, cells, hist);
    scan_kernel<<<dim3(B), dim3(1024), 0, stream>>>(hist);
    scatter_kernel<<<dim3(B * 8), dim3(512), 0, stream>>>(pref, cells, hist, wxyzw, widx);
    bbox_kernel<<<dim3(B * NBLK / 8), dim3(512), 0, stream>>>(wxyzw, wbb);
    knn_main_kernel<<<dim3(nblocks), dim3(256), 0, stream>>>(ppred, wxyzw, widx, wbb, partials, NQ);
    reduce_kernel<<<dim3(1), dim3(1024), 0, stream>>>(partials, nblocks, out, scale);
}

// Round 21
// 65.720 us; speedup vs baseline: 1.0658x; 1.0658x over previous
//
#include <hip/hip_runtime.h>

#define NPTS  4096
#define KNN   16
#define K1    17            // KNN + self
#define NBLK  64            // candidate blocks per batch == wave width
#define CELLS 4096          // 16^3 Morton cells
#define EPSF  1e-10f

__device__ __forceinline__ unsigned umin_(unsigned a, unsigned b) { return a < b ? a : b; }
__device__ __forceinline__ unsigned umax_(unsigned a, unsigned b) { return a < b ? b : a; }
__device__ __forceinline__ unsigned rdlane(unsigned v, int l) {
    return (unsigned)__builtin_amdgcn_readlane((int)v, l);
}

// cheap cross-lane primitives (DPP = VALU, ds_swizzle = DS pipe, shfl = ds_permute)
#define DPP_XOR1(v)  ((unsigned)__builtin_amdgcn_update_dpp(0, (int)(v), 0xB1, 0xF, 0xF, true))
#define DPP_XOR2(v)  ((unsigned)__builtin_amdgcn_update_dpp(0, (int)(v), 0x4E, 0xF, 0xF, true))
#define SWZ_XOR(v,J) ((unsigned)__builtin_amdgcn_ds_swizzle((int)(v), ((J) << 10) | 0x1F))
#define DPP_SHR1(v)  ((unsigned)__builtin_amdgcn_update_dpp(0, (int)(v), 0x111, 0xF, 0xF, true))
#define DPPF_SHR(vf, CTRL) __uint_as_float((unsigned)__builtin_amdgcn_update_dpp(0, (int)__float_as_uint(vf), CTRL, 0xF, 0xF, true))
#define LXOR1(v)  DPP_XOR1(v)
#define LXOR2(v)  DPP_XOR2(v)
#define LXOR4(v)  SWZ_XOR(v, 4)
#define LXOR8(v)  SWZ_XOR(v, 8)
#define LXOR16(v) SWZ_XOR(v, 16)
#define LXOR32(v) ((unsigned)__shfl_xor((int)(v), 32))

// one compare-exchange stage applied to BOTH sort chains (ILP)
#define BSTEP(K, XORF) do {                                                   \
    unsigned o1_ = XORF(arr), o2_ = XORF(bk);                                 \
    bool tm_ = (((lane & (J_)) == 0) == ((lane & (K)) == 0));                 \
    unsigned mn1_ = umin_(arr, o1_), mx1_ = umax_(arr, o1_);                  \
    unsigned mn2_ = umin_(bk, o2_),  mx2_ = umax_(bk, o2_);                   \
    arr = tm_ ? mn1_ : mx1_; bk = tm_ ? mn2_ : mx2_;                          \
} while (0)

// spread 4 bits to positions 0,3,6,9
__device__ __forceinline__ unsigned sp4(int v) {
    unsigned x = (unsigned)v;
    return (x & 1u) | ((x & 2u) << 2) | ((x & 4u) << 4) | ((x & 8u) << 6);
}

// ---- Kernel 1: per-batch counting sort by 12-bit Morton cell (monolithic;
// splitting it into chip-wide sub-kernels cost more in launch gaps than it
// saved — R20). Sort is permutation-only; exactness never depends on it.
__global__ __launch_bounds__(1024) void sort_kernel(
    const float* __restrict__ pref,
    float4* __restrict__ wxyzw, int* __restrict__ widx)
{
    __shared__ unsigned hist[CELLS];          // 16 KB
    __shared__ unsigned short cells[NPTS];    // 8 KB
    __shared__ unsigned wofs[16];
    const int tid  = threadIdx.x;
    const int lane = tid & 63, w = tid >> 6;
    const int b = blockIdx.x;
    const float* prb = pref + (size_t)b * NPTS * 3;
    const size_t base = (size_t)b * NPTS;

    for (int t = tid; t < CELLS; t += 1024) hist[t] = 0u;
    __syncthreads();

    for (int p = tid; p < NPTS; p += 1024) {
        float x = prb[3 * p + 0], y = prb[3 * p + 1], z = prb[3 * p + 2];
        int cx = min(15, max(0, (int)((x + 4.0f) * 2.0f)));
        int cy = min(15, max(0, (int)((y + 4.0f) * 2.0f)));
        int cz = min(15, max(0, (int)((z + 4.0f) * 2.0f)));
        unsigned m = sp4(cx) | (sp4(cy) << 1) | (sp4(cz) << 2);
        cells[p] = (unsigned short)m;
        atomicAdd(&hist[m], 1u);
    }
    __syncthreads();

    // Exclusive scan of hist[4096]; thread t owns cells 4t..4t+3.
    unsigned l0 = hist[4 * tid + 0], l1 = hist[4 * tid + 1];
    unsigned l2 = hist[4 * tid + 2], l3 = hist[4 * tid + 3];
    unsigned s = l0 + l1 + l2 + l3;
    unsigned run = s;
#pragma unroll
    for (int d = 1; d < 64; d <<= 1) {
        unsigned o = __shfl_up(run, d);
        if (lane >= d) run += o;
    }
    if (lane == 63) wofs[w] = run;
    __syncthreads();
    if (tid == 0) {
        unsigned acc = 0;
#pragma unroll
        for (int k = 0; k < 16; ++k) { unsigned t2 = wofs[k]; wofs[k] = acc; acc += t2; }
    }
    __syncthreads();
    unsigned excl = wofs[w] + run - s;
    hist[4 * tid + 0] = excl;
    hist[4 * tid + 1] = excl + l0;
    hist[4 * tid + 2] = excl + l0 + l1;
    hist[4 * tid + 3] = excl + l0 + l1 + l2;
    __syncthreads();

    for (int p = tid; p < NPTS; p += 1024) {
        unsigned c = cells[p];
        unsigned pos = atomicAdd(&hist[c], 1u);
        wxyzw[base + pos] = make_float4(prb[3 * p + 0], prb[3 * p + 1], prb[3 * p + 2], 0.f);
        widx[base + pos]  = p;
    }
}

// ---- Kernel 1b: per-64-block bboxes, one bbox per wave (chip-parallel).
// True min/max of actual points -> pruning exactness preserved.
__global__ __launch_bounds__(512) void bbox_kernel(
    const float4* __restrict__ wxyzw, float4* __restrict__ wbb)
{
    const int lane = threadIdx.x & 63;
    const int gb = blockIdx.x * 8 + (threadIdx.x >> 6);   // global bbox id
    const int b  = gb >> 6;                                // NBLK per batch
    const int blk = gb & (NBLK - 1);
    const size_t base = (size_t)b * NPTS;

    float4 c = wxyzw[base + blk * 64 + lane];
    float mnx = c.x, mxx = c.x, mny = c.y, mxy2 = c.y, mnz = c.z, mxz = c.z;
#pragma unroll
    for (int d = 32; d > 0; d >>= 1) {
        mnx  = fminf(mnx,  __shfl_xor(mnx,  d));
        mxx  = fmaxf(mxx,  __shfl_xor(mxx,  d));
        mny  = fminf(mny,  __shfl_xor(mny,  d));
        mxy2 = fmaxf(mxy2, __shfl_xor(mxy2, d));
        mnz  = fminf(mnz,  __shfl_xor(mnz,  d));
        mxz  = fmaxf(mxz,  __shfl_xor(mxz,  d));
    }
    if (lane == 0) {
        wbb[(size_t)gb * 2 + 0] = make_float4(mnx, mny, mnz, 0.f);
        wbb[(size_t)gb * 2 + 1] = make_float4(mxx, mxy2, mxz, 0.f);
    }
}

// DPP-based insertion of broadcast key kk_ into lane-sliced sorted arr
#define EVENTS(KEY) do {                                                      \
    unsigned long long m_ = __ballot((KEY) < thr);                            \
    if (m_) {                                                                 \
        do {                                                                  \
            int l_ = __ffsll(m_) - 1;                                         \
            m_ &= m_ - 1;                                                     \
            unsigned kk_ = rdlane(KEY, l_);                                   \
            unsigned long long lt_ = __ballot(arr < kk_) & 0x1FFFFull;        \
            int pos_ = __popcll(lt_);                                         \
            unsigned up_ = DPP_SHR1(arr);                                     \
            unsigned a15_ = rdlane(arr, 15);                                  \
            up_ = (lane == 16) ? a15_ : up_;                                  \
            arr = (lane == pos_) ? kk_ : ((lane > pos_) ? up_ : arr);         \
        } while (m_);                                                         \
        thr = rdlane(arr, K1 - 1);                                            \
    } } while (0)

// ---- Kernel 2: one query per wave, hash-permuted; distance-ordered bbox
// walk with early exit; exact top-17; one contiguous partial per block.
__global__ __launch_bounds__(256, 8) void knn_main_kernel(
    const float* __restrict__ ppred,
    const float4* __restrict__ wxyzw, const int* __restrict__ widx,
    const float4* __restrict__ wbb, float* __restrict__ partials, int NQ)
{
    __shared__ float wsum[4];
    const int lane = threadIdx.x & 63;
    const int w    = threadIdx.x >> 6;
    const int wv   = blockIdx.x * 4 + w;
    // odd multiplier mod pow2 is a bijection; mixes spatial regions across waves
    const int q = ((NQ & (NQ - 1)) == 0) ? (int)(((unsigned)wv * 26765u) & (unsigned)(NQ - 1)) : wv;

    const int b = q >> 12;
    const int p = q & (NPTS - 1);              // sorted position = query
    const size_t base = (size_t)b * NPTS;
    const int p0 = p & ~63, ownblk = p >> 6;

    const float4 qc = wxyzw[base + p];         // uniform -> broadcast
    const float qx = qc.x, qy = qc.y, qz = qc.z;

    // own-block candidate keys (self d2 == +0.0 -> key = p = minimum)
    unsigned arr;
    {
        float4 c = wxyzw[base + p0 + lane];
        float dx = c.x - qx, dy = c.y - qy, dz = c.z - qz;
        float d2 = dx * dx + dy * dy + dz * dz;
        arr = (__float_as_uint(d2) & 0xFFFFF000u) | (unsigned)(p0 + lane);
    }
    // bbox lower-bound keys: same truncation as real keys; blk in the index
    // field (blk <= any j in block) => bkey <= every real key in the block.
    unsigned bk;
    {
        float4 mn4 = wbb[((size_t)b * NBLK + lane) * 2 + 0];
        float4 mx4 = wbb[((size_t)b * NBLK + lane) * 2 + 1];
        float ddx = fmaxf(fmaxf(mn4.x - qx, qx - mx4.x), 0.0f);
        float ddy = fmaxf(fmaxf(mn4.y - qy, qy - mx4.y), 0.0f);
        float ddz = fmaxf(fmaxf(mn4.z - qz, qz - mx4.z), 0.0f);
        float bd2 = ddx * ddx + ddy * ddy + ddz * ddz;
        bk = (__float_as_uint(bd2) & 0xFFFFF000u) | (unsigned)lane;
        bk = (lane == ownblk) ? 0xFFFFFFFFu : bk;   // sentinel: never walked
    }

    // joint bitonic sort of arr and bk (ascending), ILP'd through one network
    {
        int J_;
        J_ = 1;  BSTEP(2,  LXOR1);
        J_ = 2;  BSTEP(4,  LXOR2);  J_ = 1; BSTEP(4,  LXOR1);
        J_ = 4;  BSTEP(8,  LXOR4);  J_ = 2; BSTEP(8,  LXOR2);  J_ = 1; BSTEP(8,  LXOR1);
        J_ = 8;  BSTEP(16, LXOR8);  J_ = 4; BSTEP(16, LXOR4);  J_ = 2; BSTEP(16, LXOR2);  J_ = 1; BSTEP(16, LXOR1);
        J_ = 16; BSTEP(32, LXOR16); J_ = 8; BSTEP(32, LXOR8);  J_ = 4; BSTEP(32, LXOR4);  J_ = 2; BSTEP(32, LXOR2); J_ = 1; BSTEP(32, LXOR1);
        J_ = 32; BSTEP(64, LXOR32); J_ = 16; BSTEP(64, LXOR16); J_ = 8; BSTEP(64, LXOR8); J_ = 4; BSTEP(64, LXOR4); J_ = 2; BSTEP(64, LXOR2); J_ = 1; BSTEP(64, LXOR1);
    }
    unsigned thr = rdlane(arr, K1 - 1);

    // ordered walk: blocks by ascending lower bound; break = prune rest (exact:
    // truncation is monotone, bkey <= real keys, thr only decreases).
    int k = 0;
    unsigned bcur = rdlane(bk, 0);
    bool have = (bcur < thr);
    float4 cur;
    if (have) cur = wxyzw[base + (int)(bcur & 0xFFFu) * 64 + lane];
    while (have) {
        unsigned bnext = rdlane(bk, k + 1);
        bool pf = (bnext < thr);               // prefetch decision (conservative)
        float4 nxt;
        if (pf) nxt = wxyzw[base + (int)(bnext & 0xFFFu) * 64 + lane];
        int jbase = (int)(bcur & 0xFFFu) * 64;
        float dx = cur.x - qx, dy = cur.y - qy, dz = cur.z - qz;
        float d2 = dx * dx + dy * dy + dz * dz;
        unsigned key = (__float_as_uint(d2) & 0xFFFFF000u) | (unsigned)(jbase + lane);
        EVENTS(key);                           // tightens thr
        ++k;
        bcur = bnext;
        have = (bcur < thr);                   // thr only decreased: pf false => have false
        cur = nxt;
    }

    // Epilogue: lanes 1..16 hold the 16 nearest neighbors (lane 0 = self).
    const float* ppb = ppred + (size_t)b * NPTS * 3;
    const int iorig = widx[base + p];
    float s = 0.f;
    if (lane >= 1 && lane <= KNN) {
        int js = (int)(arr & 0xFFFu);
        float4 rc = wxyzw[base + js];
        float rx = rc.x - qx, ry = rc.y - qy, rz = rc.z - qz;
        float dref = sqrtf(rx * rx + ry * ry + rz * rz);
        int nj = widx[base + js];
        float px = ppb[3 * iorig + 0], py = ppb[3 * iorig + 1], pz = ppb[3 * iorig + 2];
        float ax = ppb[3 * nj + 0] - px;
        float ay = ppb[3 * nj + 1] - py;
        float az = ppb[3 * nj + 2] - pz;
        float dpred = sqrtf(ax * ax + ay * ay + az * az);
        s = fmaxf(dpred / (dref + EPSF) - 1.0f, 0.0f);
    }
    // DPP prefix-add within rows of 16; lanes 0..16 hold all nonzeros.
    s += DPPF_SHR(s, 0x111);
    s += DPPF_SHR(s, 0x112);
    s += DPPF_SHR(s, 0x114);
    s += DPPF_SHR(s, 0x118);
    float t15 = __uint_as_float(rdlane(__float_as_uint(s), 15));
    float t16 = __uint_as_float(rdlane(__float_as_uint(s), 16));

    // one partial per block (contiguous) -> cheap reduce
    if (lane == 0) wsum[w] = t15 + t16;
    __syncthreads();
    if (threadIdx.x == 0)
        partials[blockIdx.x] = (wsum[0] + wsum[1]) + (wsum[2] + wsum[3]);
}

// ---- Kernel 3: deterministic single-block final reduction (float4 loads).
__global__ __launch_bounds__(1024) void reduce_kernel(
    const float* __restrict__ partials, int n, float* __restrict__ out, float scale)
{
    __shared__ float wsum[16];
    const float4* p4 = (const float4*)partials;
    const int n4 = n >> 2;
    float s = 0.f;
    for (int idx = threadIdx.x; idx < n4; idx += 1024) {
        float4 v = p4[idx];
        s += (v.x + v.y) + (v.z + v.w);
    }
    for (int off = 32; off > 0; off >>= 1) s += __shfl_down(s, off);
    if ((threadIdx.x & 63) == 0) wsum[threadIdx.x >> 6] = s;
    __syncthreads();
    if (threadIdx.x == 0) {
        float t = 0.f;
#pragma unroll
        for (int k = 0; k < 16; ++k) t += wsum[k];
        out[0] = t * scale;
    }
}

extern "C" void kernel_launch(void* const* d_in, const int* in_sizes, int n_in,
                              void* d_out, int out_size, void* d_ws, size_t ws_size,
                              hipStream_t stream) {
    const float* pref  = (const float*)d_in[0];
    const float* ppred = (const float*)d_in[1];
    float* out = (float*)d_out;

    const int B  = in_sizes[0] / (NPTS * 3);
    const int NQ = B * NPTS;
    const int nblocks = NQ / 4;            // 4 waves/block, 1 query/wave
    const float scale = 1.0f / ((float)NQ * (float)KNN);

    char* ws = (char*)d_ws;
    float4* wxyzw = (float4*)ws;                                   // B*N*16
    int*    widx  = (int*)   (ws + (size_t)B * NPTS * 16);         // B*N*4
    float4* wbb   = (float4*)(ws + (size_t)B * NPTS * 20);         // B*64*2*16
    float*  partials = (float*)(ws + (size_t)B * NPTS * 20 + (size_t)B * NBLK * 32);

    sort_kernel<<<dim3(B), dim3(1024), 0, stream>>>(pref, wxyzw, widx);
    bbox_kernel<<<dim3(B * NBLK / 8), dim3(512), 0, stream>>>(wxyzw, wbb);
    knn_main_kernel<<<dim3(nblocks), dim3(256), 0, stream>>>(ppred, wxyzw, widx, wbb, partials, NQ);
    reduce_kernel<<<dim3(1), dim3(1024), 0, stream>>>(partials, nblocks, out, scale);
}